// Round 18
// baseline (37.714 us; speedup 1.0000x reference)
//
#include <hip/hip_runtime.h>
#include <stdint.h>
#include <string.h>
#include <algorithm>

#define NV 4096
#define NPOOL 1024
#define NB 8
#define KNB 16
#define REMOVED 0xFFFFFFFFu
// bank-deconflicted histogram index: bin b -> word (b>>4) | ((b&15)<<6)
#define HIDX(b) ((((b) >> 4) | (((b) & 15) << 6)))

struct SIdx { unsigned short v[NPOOL]; };  // 2 KB by-value kernel arg

// ---------------- Threefry-2x32 (JAX-compatible, 20 rounds), host ----------
static inline void tf2x32_host(uint32_t k0, uint32_t k1,
                               uint32_t c0, uint32_t c1,
                               uint32_t& o0, uint32_t& o1) {
  uint32_t ks0 = k0, ks1 = k1, ks2 = k0 ^ k1 ^ 0x1BD11BDAu;
  uint32_t x0 = c0 + ks0, x1 = c1 + ks1;
#define TFR(r) { x0 += x1; x1 = (x1 << (r)) | (x1 >> (32 - (r))); x1 ^= x0; }
  TFR(13) TFR(15) TFR(26) TFR(6)
  x0 += ks1; x1 += ks2 + 1u;
  TFR(17) TFR(29) TFR(16) TFR(24)
  x0 += ks2; x1 += ks0 + 2u;
  TFR(13) TFR(15) TFR(26) TFR(6)
  x0 += ks0; x1 += ks1 + 3u;
  TFR(17) TFR(29) TFR(16) TFR(24)
  x0 += ks1; x1 += ks2 + 4u;
  TFR(13) TFR(15) TFR(26) TFR(6)
  x0 += ks2; x1 += ks0 + 5u;
#undef TFR
  o0 = x0; o1 = x1;
}

// Host: replicate jax.random.permutation(key(42), 4096)[:1024]  (validated absmax=0)
static void compute_sample_idx(SIdx& out) {
  static_assert(sizeof(SIdx) == 2048, "kernarg size");
  uint64_t arr[NV];
  uint16_t x[NV], tmp[NV];
  for (int i = 0; i < NV; ++i) x[i] = (uint16_t)i;
  uint32_t kh = 0u, kl = 42u;
  for (int round = 0; round < 2; ++round) {
    uint32_t nkh, nkl, sh, sl, t0, t1;
    tf2x32_host(kh, kl, 0u, 0u, nkh, nkl);
    tf2x32_host(kh, kl, 0u, 1u, sh, sl);
    kh = nkh; kl = nkl;
    for (int i = 0; i < NV; ++i) {
      tf2x32_host(sh, sl, 0u, (uint32_t)i, t0, t1);
      arr[i] = ((uint64_t)(t0 ^ t1) << 32) | (uint32_t)i;
    }
    std::sort(arr, arr + NV);
    for (int i = 0; i < NV; ++i) tmp[i] = x[(uint32_t)(arr[i] & 0xffffffffu)];
    memcpy(x, tmp, sizeof(x));
  }
  for (int i = 0; i < NPOOL; ++i) out.v[i] = x[i];
}

// validated extraction fallback adapted to 8 warps / 8 elems per thread;
// predicate bin <= TAUB. Rare (C > 64). Exact (dist,idx) lex order.
#define FALLBACK8(D, TAUB, WIN)                                            \
  {                                                                        \
    uint32_t mask = 0;                                                     \
    for (int r = 0; r < KNB; ++r) {                                        \
      uint32_t bv = REMOVED, bm = 0xFFFFFFFFu;                             \
      _Pragma("unroll")                                                    \
      for (int t = 0; t < 8; ++t) {                                        \
        const uint32_t v = (((mask >> t) & 1u) || ((D[t] >> 22) > (TAUB))) \
                               ? REMOVED : D[t];                           \
        const uint32_t m = (uint32_t)((tid << 3) + t);                     \
        if (v < bv || (v == bv && m < bm)) { bv = v; bm = m; }             \
      }                                                                    \
      for (int off = 32; off > 0; off >>= 1) {                             \
        const uint32_t ov = (uint32_t)__shfl_down((int)bv, off);           \
        const uint32_t om = (uint32_t)__shfl_down((int)bm, off);           \
        if (ov < bv || (ov == bv && om < bm)) { bv = ov; bm = om; }        \
      }                                                                    \
      if (lane == 0) wmin[warp] = ((unsigned long long)bv << 32) | bm;     \
      __syncthreads();                                                     \
      unsigned long long best = wmin[0];                                   \
      _Pragma("unroll")                                                    \
      for (int p = 1; p < 8; ++p) { const unsigned long long c = wmin[p];  \
        if (c < best) best = c; }                                          \
      const int w = (int)(best & 0xFFFFFFFFu);                             \
      if (tid == 0) (WIN)[r] = w;                                          \
      if (tid == (w >> 3)) mask |= 1u << (w & 7);                          \
      __syncthreads();                                                     \
    }                                                                      \
  }

// ---------------- K1: 512 threads / 4 queries (same batch). 8 verts/thread
// (f[24]+4*d[8] keeps VGPR at R11 level — R12's failure was f[48]+d[64]).
// Per-query vertex traffic 12 KB (R11: 24). All 8 warps busy every phase:
// warps 0-3 scan/rank query w; gather = 2 warps/query with fmax combine.
__global__ __launch_bounds__(512) void knn_pool_kernel(
    const float* __restrict__ vertices, const float* __restrict__ fm,
    const SIdx sidx,
    float* __restrict__ outV, float* __restrict__ outF) {
  __shared__ __attribute__((aligned(16))) uint32_t hist[4][1024];
  __shared__ unsigned long long cand[4][64];
  __shared__ unsigned long long wmin[8];
  __shared__ int winners[4][KNB];
  __shared__ int s_nc[4], s_tb[4];

  const int tid = threadIdx.x;
  const int lane = tid & 63;
  const int warp = tid >> 6;
  const int blk = blockIdx.x;      // 0..2047
  const int b = blk & 7;           // XCD-aware: batch b -> XCD b (bijective)
  const int ibase = (blk >> 3) << 2;
  const int n0 = (int)sidx.v[ibase + 0];
  const int n1 = (int)sidx.v[ibase + 1];
  const int n2 = (int)sidx.v[ibase + 2];
  const int n3 = (int)sidx.v[ibase + 3];

  // zero hists FIRST (16 KB = 1024 uint4 over 512 threads)
  {
    const uint4 z4 = make_uint4(0, 0, 0, 0);
    uint4* h4 = (uint4*)&hist[0][0];
    h4[tid] = z4; h4[tid + 512] = z4;
    if (tid < 4) s_nc[tid] = 0;
  }

  const float* vb = vertices + (size_t)b * NV * 3;
  const float q0x = vb[n0 * 3 + 0], q0y = vb[n0 * 3 + 1], q0z = vb[n0 * 3 + 2];
  const float q1x = vb[n1 * 3 + 0], q1y = vb[n1 * 3 + 1], q1z = vb[n1 * 3 + 2];
  const float q2x = vb[n2 * 3 + 0], q2y = vb[n2 * 3 + 1], q2z = vb[n2 * 3 + 2];
  const float q3x = vb[n3 * 3 + 0], q3y = vb[n3 * 3 + 1], q3z = vb[n3 * 3 + 2];
  // quadratic[n]: plain mul/add (XLA reduce of squares) — validated arithmetic
  const float qn0 = __fadd_rn(__fadd_rn(__fmul_rn(q0x, q0x), __fmul_rn(q0y, q0y)), __fmul_rn(q0z, q0z));
  const float qn1 = __fadd_rn(__fadd_rn(__fmul_rn(q1x, q1x), __fmul_rn(q1y, q1y)), __fmul_rn(q1z, q1z));
  const float qn2 = __fadd_rn(__fadd_rn(__fmul_rn(q2x, q2x), __fmul_rn(q2y, q2y)), __fmul_rn(q2z, q2z));
  const float qn3 = __fadd_rn(__fadd_rn(__fmul_rn(q3x, q3x), __fmul_rn(q3y, q3y)), __fmul_rn(q3z, q3z));

  // 6 independent float4 loads: this thread's 8 vertices, 96 B contiguous
  const float4* vb4 = (const float4*)vb + tid * 6;
  float f[24];
#pragma unroll
  for (int j = 0; j < 6; ++j) {
    const float4 v4 = vb4[j];
    f[4 * j + 0] = v4.x; f[4 * j + 1] = v4.y;
    f[4 * j + 2] = v4.z; f[4 * j + 3] = v4.w;
  }

  uint32_t d0[8], d1[8], d2[8], d3[8];
#pragma unroll
  for (int t = 0; t < 8; ++t) {
    const int m = (tid << 3) + t;
    const float cx = f[3 * t + 0], cy = f[3 * t + 1], cz = f[3 * t + 2];
    const float qm = __fadd_rn(__fadd_rn(__fmul_rn(cx, cx), __fmul_rn(cy, cy)),
                               __fmul_rn(cz, cz));  // shared across 4 queries
    const float in0 = __fmaf_rn(cz, q0z, __fmaf_rn(cy, q0y, __fmul_rn(cx, q0x)));
    const float in1 = __fmaf_rn(cz, q1z, __fmaf_rn(cy, q1y, __fmul_rn(cx, q1x)));
    const float in2 = __fmaf_rn(cz, q2z, __fmaf_rn(cy, q2y, __fmul_rn(cx, q2x)));
    const float in3 = __fmaf_rn(cz, q3z, __fmaf_rn(cy, q3y, __fmul_rn(cx, q3x)));
    const float ds0 = __fadd_rn(__fadd_rn(__fmul_rn(-2.0f, in0), qm), qn0);
    const float ds1 = __fadd_rn(__fadd_rn(__fmul_rn(-2.0f, in1), qm), qn1);
    const float ds2 = __fadd_rn(__fadd_rn(__fmul_rn(-2.0f, in2), qm), qn2);
    const float ds3 = __fadd_rn(__fadd_rn(__fmul_rn(-2.0f, in3), qm), qn3);
    d0[t] = (m == n0) ? REMOVED : __float_as_uint(ds0);  // validated uint order
    d1[t] = (m == n1) ? REMOVED : __float_as_uint(ds1);
    d2[t] = (m == n2) ? REMOVED : __float_as_uint(ds2);
    d3[t] = (m == n3) ? REMOVED : __float_as_uint(ds3);
  }

  // per-thread minima
  uint32_t mn0 = d0[0], mn1 = d1[0], mn2 = d2[0], mn3 = d3[0];
#pragma unroll
  for (int t = 1; t < 8; ++t) {
    mn0 = (d0[t] < mn0) ? d0[t] : mn0;
    mn1 = (d1[t] < mn1) ? d1[t] : mn1;
    mn2 = (d2[t] < mn2) ? d2[t] : mn2;
    mn3 = (d3[t] < mn3) ? d3[t] : mn3;
  }
  __syncthreads();

  // minima histograms: 4 atomics/thread (512 minima of 8 per query; the
  // 16th-order-stat bound holds for any thread count: the 16 threads with
  // smallest minima give 16 distinct candidates <= M_(16))
  atomicAdd(&hist[0][HIDX(mn0 >> 22)], 1u);
  atomicAdd(&hist[1][HIDX(mn1 >> 22)], 1u);
  atomicAdd(&hist[2][HIDX(mn2 >> 22)], 1u);
  atomicAdd(&hist[3][HIDX(mn3 >> 22)], 1u);
  __syncthreads();

  // parallel scans: warp w<4 -> hist[w] -> s_tb[w] (validated parallel walk)
  if (warp < 4) {
    const uint32_t* H = hist[warp];   // wave-uniform
    uint32_t s = 0;
#pragma unroll
    for (int j = 0; j < 16; ++j) s += H[j * 64 + lane];  // HIDX(lane*16+j)
    uint32_t inc = s;
    for (int off = 1; off < 64; off <<= 1) {
      const uint32_t o = (uint32_t)__shfl_up((int)inc, off);
      if (lane >= off) inc += o;
    }
    const uint32_t pre = inc - s;
    const bool cross = (pre < KNB) && (inc >= KNB);
    const unsigned long long bal = __ballot(cross);
    const int g = __ffsll((unsigned long long)bal) - 1;   // crossing group
    const uint32_t c0 = (uint32_t)__shfl((int)pre, g);    // prefix before group
    const uint32_t h = (lane < 16) ? H[lane * 64 + g] : 0u;
    uint32_t hin = h;
    for (int off = 1; off < 16; off <<= 1) {
      const uint32_t o = (uint32_t)__shfl_up((int)hin, off);
      if (lane >= off) hin += o;
    }
    const uint32_t incj = c0 + hin;
    const bool crossj = (lane < 16) && ((incj - h) < KNB) && (incj >= KNB);
    const unsigned long long bal2 = __ballot(crossj);
    const int jstar = __ffsll((unsigned long long)bal2) - 1;
    if (lane == 0) s_tb[warp] = g * 16 + jstar;
  }
  __syncthreads();

  const uint32_t taub0 = (uint32_t)s_tb[0];
  const uint32_t taub1 = (uint32_t)s_tb[1];
  const uint32_t taub2 = (uint32_t)s_tb[2];
  const uint32_t taub3 = (uint32_t)s_tb[3];

  // append candidates with bin <= taub (superset of exact top-16; C >= 16)
#pragma unroll
  for (int t = 0; t < 8; ++t) {
    const uint32_t m = (uint32_t)((tid << 3) + t);
    const uint32_t v0 = d0[t];
    if ((v0 >> 22) <= taub0) {
      const int s = atomicAdd(&s_nc[0], 1);
      if (s < 64) cand[0][s] = ((unsigned long long)v0 << 32) | m;
    }
    const uint32_t v1 = d1[t];
    if ((v1 >> 22) <= taub1) {
      const int s = atomicAdd(&s_nc[1], 1);
      if (s < 64) cand[1][s] = ((unsigned long long)v1 << 32) | m;
    }
    const uint32_t v2 = d2[t];
    if ((v2 >> 22) <= taub2) {
      const int s = atomicAdd(&s_nc[2], 1);
      if (s < 64) cand[2][s] = ((unsigned long long)v2 << 32) | m;
    }
    const uint32_t v3 = d3[t];
    if ((v3 >> 22) <= taub3) {
      const int s = atomicAdd(&s_nc[3], 1);
      if (s < 64) cand[3][s] = ((unsigned long long)v3 << 32) | m;
    }
  }
  __syncthreads();

  const int C0 = s_nc[0], C1 = s_nc[1], C2 = s_nc[2], C3 = s_nc[3];
  // per-lane rank selection: warp w<4 ranks query w (C==16 shortcut)
  if (warp < 4) {
    const int C = s_nc[warp];
    if (C <= 64) {
      if (C == KNB) {
        if (lane < KNB) winners[warp][lane] = (int)(cand[warp][lane] & 0xFFFFFFFFu);
      } else {
        const unsigned long long me =
            (lane < C) ? cand[warp][lane] : 0xFFFFFFFFFFFFFFFFull;
        int rank = 0;
        for (int j = 0; j < C; ++j) rank += (cand[warp][j] < me) ? 1 : 0;
        if (lane < C && rank < KNB) winners[warp][rank] = (int)(me & 0xFFFFFFFFu);
      }
    }
  }
  __syncthreads();

  // rare fallbacks (block-uniform conditions, barriers inside)
  if (C0 > 64) FALLBACK8(d0, taub0, winners[0]);
  if (C1 > 64) FALLBACK8(d1, taub1, winners[1]);
  if (C2 > 64) FALLBACK8(d2, taub2, winners[2]);
  if (C3 > 64) FALLBACK8(d3, taub3, winners[3]);

  // gather + max: 2 warps per query (halves 0/1), fmax combine via LDS
  // (aliases dead hist area; exact — max is associative/commutative)
  const float* fmb = fm + (size_t)b * NV * 256;
  {
    const int q = warp & 3;
    const int half = warp >> 2;          // 0 or 1
    const int* W = winners[q];
    float4 acc = make_float4(-INFINITY, -INFINITY, -INFINITY, -INFINITY);
#pragma unroll
    for (int s = 0; s < 8; ++s) {
      const float4 v = ((const float4*)(fmb + (size_t)W[half * 8 + s] * 256))[lane];
      acc.x = fmaxf(acc.x, v.x); acc.y = fmaxf(acc.y, v.y);
      acc.z = fmaxf(acc.z, v.z); acc.w = fmaxf(acc.w, v.w);
    }
    float4* part = (float4*)&hist[0][0];   // 4 q * 64 lanes * 16 B = 4 KB
    if (half == 1) {
      part[q * 64 + lane] = acc;
      if (lane < 3) {
        const int nq = (q == 0) ? n0 : (q == 1) ? n1 : (q == 2) ? n2 : n3;
        outV[((size_t)b * NPOOL + ibase + q) * 3 + lane] = vb[nq * 3 + lane];
      }
    }
    __syncthreads();
    if (half == 0) {
      const float4 o = part[q * 64 + lane];
      acc.x = fmaxf(acc.x, o.x); acc.y = fmaxf(acc.y, o.y);
      acc.z = fmaxf(acc.z, o.z); acc.w = fmaxf(acc.w, o.w);
      ((float4*)(outF + ((size_t)b * NPOOL + ibase + q) * 256))[lane] = acc;
    }
  }
}

extern "C" void kernel_launch(void* const* d_in, const int* in_sizes, int n_in,
                              void* d_out, int out_size, void* d_ws, size_t ws_size,
                              hipStream_t stream) {
  const float* vertices = (const float*)d_in[0];
  const float* fm = (const float*)d_in[1];
  float* out = (float*)d_out;
  float* outV = out;                      // (8, 1024, 3)
  float* outF = out + NB * NPOOL * 3;     // (8, 1024, 256)

  SIdx sidx;
  compute_sample_idx(sidx);               // pure host constant of key(42)

  knn_pool_kernel<<<NB * NPOOL / 4, 512, 0, stream>>>(vertices, fm, sidx, outV, outF);
}